// Round 1
// baseline (1148.000 us; speedup 1.0000x reference)
//
#include <hip/hip_runtime.h>
#include <cstdint>
#include <cstddef>

#define NN 100000
#define EE 1600000
#define HH 128
#define NB_N 391   // ceil(NN/256)
#define NB_E 6250  // ceil(EE/256)

static __device__ __forceinline__ unsigned fsort_(float f){
  unsigned u = __float_as_uint(f);
  return (u & 0x80000000u) ? ~u : (u | 0x80000000u);
}
static __device__ __forceinline__ float unfsort_(unsigned u){
  unsigned v = (u & 0x80000000u) ? (u & 0x7FFFFFFFu) : ~u;
  return __uint_as_float(v);
}

// ---------- edge dtype probe (int64 vs int32 layout) ----------
__global__ void k_edgeflag(const int* __restrict__ ei, unsigned* __restrict__ state){
  int t = threadIdx.x; // 64 threads
  int v = ei[2*t + 1];
  unsigned long long m = __ballot(v != 0);
  if(t == 0) state[8] = (m == 0ull) ? 1u : 0u; // 1 => int64 layout
}
__global__ void k_edgecopy(const int* __restrict__ ei, const unsigned* __restrict__ state,
                           int* __restrict__ esrc, int* __restrict__ edst){
  int e = blockIdx.x*256 + threadIdx.x;
  if(e >= EE) return;
  if(state[8]){
    esrc[e] = ei[2*e];
    edst[e] = ei[2*EE + 2*e];
  } else {
    esrc[e] = ei[e];
    edst[e] = ei[EE + e];
  }
}

// ---------- init ----------
__global__ void k_init(float* __restrict__ nm, float* __restrict__ racc_mean,
                       unsigned* __restrict__ racc_max){
  int i = blockIdx.x*256 + threadIdx.x;
  if(i < NN) nm[i] = 1.f;
  if(i < 3*HH){ racc_mean[i] = 0.f; racc_max[i] = fsort_(-1e30f); }
}

// ---------- CSR build ----------
__global__ void k_count(const int* __restrict__ dst, int* __restrict__ cnt){
  int e = blockIdx.x*256 + threadIdx.x;
  if(e < EE) atomicAdd(&cnt[dst[e]], 1);
}
__global__ void k_blocksum(const int* __restrict__ cnt, int* __restrict__ bsum){
  __shared__ int sm[256];
  int i = blockIdx.x*256 + threadIdx.x;
  sm[threadIdx.x] = (i < NN) ? cnt[i] : 0;
  __syncthreads();
  for(int off=128; off>0; off>>=1){
    if(threadIdx.x < off) sm[threadIdx.x] += sm[threadIdx.x+off];
    __syncthreads();
  }
  if(threadIdx.x == 0) bsum[blockIdx.x] = sm[0];
}
__global__ void k_exscan(int* __restrict__ data, int nb){
  __shared__ int sm[512];
  int t = threadIdx.x;
  int orig = (t < nb) ? data[t] : 0;
  sm[t] = orig;
  __syncthreads();
  for(int off=1; off<512; off<<=1){
    int v = (t >= off) ? sm[t-off] : 0;
    __syncthreads();
    sm[t] += v;
    __syncthreads();
  }
  if(t < nb) data[t] = sm[t] - orig;
}
__global__ void k_scanC(const int* __restrict__ cnt, const int* __restrict__ boff,
                        int* __restrict__ row_ptr, int* __restrict__ fill){
  __shared__ int sm[256];
  int t = threadIdx.x;
  int i = blockIdx.x*256 + t;
  int orig = (i < NN) ? cnt[i] : 0;
  sm[t] = orig;
  __syncthreads();
  for(int off=1; off<256; off<<=1){
    int v = (t >= off) ? sm[t-off] : 0;
    __syncthreads();
    sm[t] += v;
    __syncthreads();
  }
  if(i < NN){ row_ptr[i] = boff[blockIdx.x] + sm[t] - orig; fill[i] = 0; }
  if(i == 0) row_ptr[NN] = EE;
}
__global__ void k_fill(const int* __restrict__ src, const int* __restrict__ dst,
                       const int* __restrict__ row_ptr, int* __restrict__ fill,
                       int* __restrict__ col){
  int e = blockIdx.x*256 + threadIdx.x;
  if(e < EE){
    int d = dst[e];
    int pos = atomicAdd(&fill[d], 1);
    col[row_ptr[d] + pos] = src[e];
  }
}

// ---------- per-layer kernels ----------
__global__ void k_deg(const float* __restrict__ nm, const int* __restrict__ row_ptr,
                      const int* __restrict__ col, float* __restrict__ dinv){
  int i = blockIdx.x*256 + threadIdx.x;
  if(i >= NN) return;
  float d = 0.f;
  if(nm[i] > 0.f){
    int e0 = row_ptr[i], e1 = row_ptr[i+1];
    float s = 1.f;
    for(int e=e0; e<e1; e++) s += nm[col[e]];
    d = s;
  }
  dinv[i] = (d > 0.f) ? (1.f/sqrtf(d)) : 0.f;
}

// y = x @ W  (N x 128 @ 128 x 128, fp32, 64x64 tile, 4x4 microtile)
__global__ __launch_bounds__(256) void k_gemm(const float* __restrict__ x,
                                              const float* __restrict__ W,
                                              float* __restrict__ y){
  __shared__ float sX[16][68];
  __shared__ float sW[16][64];
  int row0 = blockIdx.x*64, col0 = blockIdx.y*64;
  int t = threadIdx.x;
  int tx = t & 15, ty = t >> 4;
  float acc[4][4] = {{0.f}};
  for(int kb=0; kb<HH; kb+=16){
    #pragma unroll
    for(int j=0;j<4;j++){
      int r = (t>>4) + j*16;
      int k = t & 15;
      int gr = row0 + r;
      sX[k][r] = (gr < NN) ? x[(size_t)gr*HH + kb + k] : 0.f;
    }
    #pragma unroll
    for(int j=0;j<4;j++){
      int k = (t>>6) + j*4;
      int c = t & 63;
      sW[k][c] = W[(size_t)(kb+k)*HH + col0 + c];
    }
    __syncthreads();
    #pragma unroll
    for(int k=0;k<16;k++){
      float4 xv = *(const float4*)&sX[k][ty*4];
      float4 wv = *(const float4*)&sW[k][tx*4];
      float xs[4] = {xv.x, xv.y, xv.z, xv.w};
      float wsv[4] = {wv.x, wv.y, wv.z, wv.w};
      #pragma unroll
      for(int a=0;a<4;a++)
        #pragma unroll
        for(int b=0;b<4;b++)
          acc[a][b] += xs[a]*wsv[b];
    }
    __syncthreads();
  }
  #pragma unroll
  for(int a=0;a<4;a++){
    int gr = row0 + ty*4 + a;
    if(gr < NN){
      float4 o = make_float4(acc[a][0],acc[a][1],acc[a][2],acc[a][3]);
      *(float4*)&y[(size_t)gr*HH + col0 + tx*4] = o;
    }
  }
}

// h = relu(dinv_i * sum_s dinv_s*y_s + dinv_i^2*y_i + b); p = h . ws
// 16 lanes per dst node, 8 floats/lane
__global__ __launch_bounds__(256) void k_agg(const float* __restrict__ y, const float* __restrict__ dinv,
                     const int* __restrict__ row_ptr, const int* __restrict__ col,
                     const float* __restrict__ bias, const float* __restrict__ wsc,
                     float* __restrict__ h, float* __restrict__ p){
  int gid = blockIdx.x*256 + threadIdx.x;
  int node = gid >> 4;
  int lane = gid & 15;
  if(node >= NN) return;
  float di = dinv[node];
  if(di == 0.f) return;
  float a0x=0,a0y=0,a0z=0,a0w=0, a1x=0,a1y=0,a1z=0,a1w=0;
  int e0 = row_ptr[node], e1 = row_ptr[node+1];
  for(int e=e0; e<e1; e++){
    int s = col[e];
    float ds = dinv[s];
    if(ds != 0.f){
      const float4* yr = (const float4*)(y + (size_t)s*HH);
      float4 v0 = yr[lane];
      float4 v1 = yr[lane+16];
      a0x += ds*v0.x; a0y += ds*v0.y; a0z += ds*v0.z; a0w += ds*v0.w;
      a1x += ds*v1.x; a1y += ds*v1.y; a1z += ds*v1.z; a1w += ds*v1.w;
    }
  }
  const float4* yi = (const float4*)(y + (size_t)node*HH);
  float4 s0 = yi[lane], s1 = yi[lane+16];
  const float4* b4 = (const float4*)bias;
  float4 bb0 = b4[lane], bb1 = b4[lane+16];
  float d2 = di*di;
  float o0x = fmaxf(di*a0x + d2*s0.x + bb0.x, 0.f);
  float o0y = fmaxf(di*a0y + d2*s0.y + bb0.y, 0.f);
  float o0z = fmaxf(di*a0z + d2*s0.z + bb0.z, 0.f);
  float o0w = fmaxf(di*a0w + d2*s0.w + bb0.w, 0.f);
  float o1x = fmaxf(di*a1x + d2*s1.x + bb1.x, 0.f);
  float o1y = fmaxf(di*a1y + d2*s1.y + bb1.y, 0.f);
  float o1z = fmaxf(di*a1z + d2*s1.z + bb1.z, 0.f);
  float o1w = fmaxf(di*a1w + d2*s1.w + bb1.w, 0.f);
  float4* hr = (float4*)(h + (size_t)node*HH);
  hr[lane]    = make_float4(o0x,o0y,o0z,o0w);
  hr[lane+16] = make_float4(o1x,o1y,o1z,o1w);
  const float4* w4 = (const float4*)wsc;
  float4 w0 = w4[lane], w1 = w4[lane+16];
  float pp = o0x*w0.x + o0y*w0.y + o0z*w0.z + o0w*w0.w
           + o1x*w1.x + o1y*w1.y + o1z*w1.z + o1w*w1.w;
  pp += __shfl_xor(pp, 1, 64);
  pp += __shfl_xor(pp, 2, 64);
  pp += __shfl_xor(pp, 4, 64);
  pp += __shfl_xor(pp, 8, 64);
  if(lane == 0) p[node] = pp;
}

__global__ void k_score(const float* __restrict__ p, const float* __restrict__ dinv,
                        const int* __restrict__ row_ptr, const int* __restrict__ col,
                        const float* __restrict__ bs, float* __restrict__ score,
                        unsigned* __restrict__ key){
  int i = blockIdx.x*256 + threadIdx.x;
  if(i >= NN) return;
  float di = dinv[i];
  if(di == 0.f){ key[i] = 0u; return; }
  float s = 0.f;
  int e0 = row_ptr[i], e1 = row_ptr[i+1];
  for(int e=e0; e<e1; e++){
    int c = col[e];
    float ds = dinv[c];
    if(ds != 0.f) s += ds*p[c];
  }
  float sc = di*s + di*di*p[i] + bs[0];
  score[i] = sc;
  key[i] = fsort_(sc);
}

// ---------- radix select (2x16-bit) ----------
__global__ void k_hist_hi(const unsigned* __restrict__ key, unsigned* __restrict__ hist){
  int i = blockIdx.x*256 + threadIdx.x;
  if(i < NN){
    unsigned kv = key[i];
    if(kv) atomicAdd(&hist[kv>>16], 1u);
  }
}
__global__ void k_hist_lo(const unsigned* __restrict__ key, const unsigned* __restrict__ state,
                          unsigned* __restrict__ histB){
  int i = blockIdx.x*256 + threadIdx.x;
  if(i < NN){
    unsigned kv = key[i];
    if((kv >> 16) == state[0]) atomicAdd(&histB[kv & 0xFFFFu], 1u);
  }
}
__global__ void k_pick(const unsigned* __restrict__ hist, unsigned* __restrict__ state,
                       int k_in, int mode){
  __shared__ unsigned csum[256];
  int t = threadIdx.x;
  const uint4* h4 = (const uint4*)(hist + t*256);
  unsigned s = 0;
  for(int j=0;j<64;j++){ uint4 v = h4[j]; s += v.x+v.y+v.z+v.w; }
  csum[t] = s;
  __syncthreads();
  for(int off=1; off<256; off<<=1){
    unsigned v = (t+off < 256) ? csum[t+off] : 0u;
    __syncthreads();
    csum[t] += v;
    __syncthreads();
  }
  unsigned k = (mode == 0) ? (unsigned)k_in : state[1];
  unsigned above = csum[t] - s;
  if(above < k && above + s >= k){
    unsigned run = above;
    for(int j=255; j>=0; j--){
      unsigned c = hist[t*256+j];
      if(run + c >= k){
        if(mode == 0){ state[0] = (unsigned)(t*256+j); state[1] = k - run; }
        else { state[2] = (state[0] << 16) | (unsigned)(t*256+j); state[3] = k - run; }
        break;
      }
      run += c;
    }
  }
}

// ---------- tie ranking + mask + gate + readout ----------
__global__ void k_maskA(const unsigned* __restrict__ key, const unsigned* __restrict__ state,
                        int* __restrict__ bcnt){
  __shared__ int c4[4];
  int t = threadIdx.x;
  int i = blockIdx.x*256 + t;
  unsigned T = state[2];
  bool match = (i < NN) && (key[i] == T);
  unsigned long long m = __ballot(match);
  if((t & 63) == 0) c4[t >> 6] = __popcll(m);
  __syncthreads();
  if(t == 0) bcnt[blockIdx.x] = c4[0]+c4[1]+c4[2]+c4[3];
}

__global__ __launch_bounds__(256) void k_maskC(const unsigned* __restrict__ key, const float* __restrict__ score,
                       const int* __restrict__ boff, const unsigned* __restrict__ state,
                       float* __restrict__ h, float* __restrict__ nm,
                       float* __restrict__ racc_mean, unsigned* __restrict__ racc_max, int layer){
  __shared__ float gl[256];
  __shared__ unsigned char slf[256];
  __shared__ int wcnt[4];
  __shared__ float4 red[256];
  int t = threadIdx.x;
  int i = blockIdx.x*256 + t;
  unsigned T = state[2];
  int trem = (int)state[3];
  unsigned kv = (i < NN) ? key[i] : 0u;
  bool match = (kv == T);
  unsigned long long m = __ballot(match);
  int lane = t & 63, wid = t >> 6;
  if(lane == 0) wcnt[wid] = __popcll(m);
  __syncthreads();
  int pre = 0;
  for(int w=0; w<wid; w++) pre += wcnt[w];
  int lrank = __popcll(m & ((1ull << lane) - 1ull));
  int rank = boff[blockIdx.x] + pre + lrank;
  bool sel = (kv > T) || (match && rank < trem);
  float g = 0.f;
  if(sel) g = tanhf(score[i]);
  gl[t] = g;
  slf[t] = sel ? 1 : 0;
  if(i < NN) nm[i] = sel ? 1.f : 0.f;
  __syncthreads();
  int ch = t & 31;
  int nb = t >> 5;
  float mx_=0.f, my_=0.f, mz_=0.f, mw_=0.f;
  float Mx=-1e30f, My=-1e30f, Mz=-1e30f, Mw=-1e30f;
  int base = blockIdx.x*256;
  for(int itr=0; itr<32; itr++){
    int nl = nb + itr*8;
    int node = base + nl;
    if(node < NN){
      float gg = gl[nl];
      float4* hp = (float4*)(h + (size_t)node*HH) + ch;
      float4 v = *hp;
      v.x *= gg; v.y *= gg; v.z *= gg; v.w *= gg;
      *hp = v;
      mx_ += v.x; my_ += v.y; mz_ += v.z; mw_ += v.w;
      if(slf[nl]){
        Mx = fmaxf(Mx, v.x); My = fmaxf(My, v.y);
        Mz = fmaxf(Mz, v.z); Mw = fmaxf(Mw, v.w);
      }
    }
  }
  red[t] = make_float4(mx_,my_,mz_,mw_);
  __syncthreads();
  if(t < 32){
    float4 sacc = red[t];
    for(int j=1;j<8;j++){
      float4 o = red[t + 32*j];
      sacc.x += o.x; sacc.y += o.y; sacc.z += o.z; sacc.w += o.w;
    }
    int d = layer*HH + t*4;
    atomicAdd(&racc_mean[d+0], sacc.x);
    atomicAdd(&racc_mean[d+1], sacc.y);
    atomicAdd(&racc_mean[d+2], sacc.z);
    atomicAdd(&racc_mean[d+3], sacc.w);
  }
  __syncthreads();
  red[t] = make_float4(Mx,My,Mz,Mw);
  __syncthreads();
  if(t < 32){
    float4 sacc = red[t];
    for(int j=1;j<8;j++){
      float4 o = red[t + 32*j];
      sacc.x = fmaxf(sacc.x,o.x); sacc.y = fmaxf(sacc.y,o.y);
      sacc.z = fmaxf(sacc.z,o.z); sacc.w = fmaxf(sacc.w,o.w);
    }
    int d = layer*HH + t*4;
    atomicMax(&racc_max[d+0], fsort_(sacc.x));
    atomicMax(&racc_max[d+1], fsort_(sacc.y));
    atomicMax(&racc_max[d+2], fsort_(sacc.z));
    atomicMax(&racc_max[d+3], fsort_(sacc.w));
  }
}

// ---------- MLP head + log_softmax ----------
__global__ void k_mlp(const float* __restrict__ racc_mean, const unsigned* __restrict__ racc_max,
                      const float* __restrict__ M1, const float* __restrict__ bm1,
                      const float* __restrict__ M2, const float* __restrict__ bm2,
                      const float* __restrict__ M3, const float* __restrict__ bm3,
                      float* __restrict__ out){
  __shared__ float R[256];
  __shared__ float y1[128];
  __shared__ float y2[64];
  __shared__ float y3[16];
  int t = threadIdx.x;
  if(t < 128){
    R[t] = racc_mean[t]/50000.f + racc_mean[128+t]/25000.f + racc_mean[256+t]/12500.f;
    R[128+t] = unfsort_(racc_max[t]) + unfsort_(racc_max[128+t]) + unfsort_(racc_max[256+t]);
  }
  __syncthreads();
  if(t < 128){
    float a = bm1[t];
    for(int d=0; d<256; d++) a += R[d]*M1[d*128+t];
    y1[t] = fmaxf(a, 0.f);
  }
  __syncthreads();
  if(t < 64){
    float a = bm2[t];
    for(int d=0; d<128; d++) a += y1[d]*M2[d*64+t];
    y2[t] = fmaxf(a, 0.f);
  }
  __syncthreads();
  if(t < 10){
    float a = bm3[t];
    for(int d=0; d<64; d++) a += y2[d]*M3[d*10+t];
    y3[t] = a;
  }
  __syncthreads();
  if(t == 0){
    float mx = -1e30f;
    for(int o=0;o<10;o++) mx = fmaxf(mx, y3[o]);
    float s = 0.f;
    for(int o=0;o<10;o++) s += expf(y3[o]-mx);
    float ls = logf(s);
    for(int o=0;o<10;o++) out[o] = y3[o] - mx - ls;
  }
}

extern "C" void kernel_launch(void* const* d_in, const int* in_sizes, int n_in,
                              void* d_out, int out_size, void* d_ws, size_t ws_size,
                              hipStream_t stream){
  (void)in_sizes; (void)n_in; (void)out_size; (void)ws_size;
  const float* x  = (const float*)d_in[0];
  const int*   ei = (const int*)d_in[1];
  const float* W[3]   = {(const float*)d_in[2],  (const float*)d_in[6],  (const float*)d_in[10]};
  const float* bb[3]  = {(const float*)d_in[3],  (const float*)d_in[7],  (const float*)d_in[11]};
  const float* wsc[3] = {(const float*)d_in[4],  (const float*)d_in[8],  (const float*)d_in[12]};
  const float* bsc[3] = {(const float*)d_in[5],  (const float*)d_in[9],  (const float*)d_in[13]};
  const float* M1  = (const float*)d_in[14];
  const float* bm1 = (const float*)d_in[15];
  const float* M2  = (const float*)d_in[16];
  const float* bm2 = (const float*)d_in[17];
  const float* M3  = (const float*)d_in[18];
  const float* bm3 = (const float*)d_in[19];
  float* out = (float*)d_out;

  char* base = (char*)d_ws;
  size_t off = 0;
  auto alloc = [&](size_t bytes)->char*{
    char* ptr = base + off;
    off += (bytes + 511) & ~(size_t)511;
    return ptr;
  };
  float*    bufA      = (float*)   alloc((size_t)NN*HH*4);
  float*    bufB      = (float*)   alloc((size_t)NN*HH*4);
  int*      col       = (int*)     alloc((size_t)EE*4);
  int*      esrc      = (int*)     alloc((size_t)EE*4);
  int*      edst      = (int*)     alloc((size_t)EE*4);
  int*      row_ptr   = (int*)     alloc((size_t)(NN+1)*4);
  int*      cnt       = (int*)     alloc((size_t)NN*4);
  int*      fill      = (int*)     alloc((size_t)NN*4);
  float*    dinv      = (float*)   alloc((size_t)NN*4);
  float*    nm        = (float*)   alloc((size_t)NN*4);
  float*    pbuf      = (float*)   alloc((size_t)NN*4);
  float*    score     = (float*)   alloc((size_t)NN*4);
  unsigned* key       = (unsigned*)alloc((size_t)NN*4);
  unsigned* hist      = (unsigned*)alloc((size_t)2*65536*4);
  unsigned* state     = (unsigned*)alloc(256);
  int*      bsum      = (int*)     alloc(2048);
  int*      bcnt      = (int*)     alloc(2048);
  float*    racc_mean = (float*)   alloc(3*HH*4);
  unsigned* racc_max  = (unsigned*)alloc(3*HH*4);

  // edge normalize (handles int64 or int32 layout)
  k_edgeflag<<<1,64,0,stream>>>(ei, state);
  k_edgecopy<<<NB_E,256,0,stream>>>(ei, state, esrc, edst);

  // CSR build (by dst)
  hipMemsetAsync(cnt, 0, (size_t)NN*4, stream);
  k_count<<<NB_E,256,0,stream>>>(edst, cnt);
  k_blocksum<<<NB_N,256,0,stream>>>(cnt, bsum);
  k_exscan<<<1,512,0,stream>>>(bsum, NB_N);
  k_scanC<<<NB_N,256,0,stream>>>(cnt, bsum, row_ptr, fill);
  k_fill<<<NB_E,256,0,stream>>>(esrc, edst, row_ptr, fill, col);
  k_init<<<NB_N,256,0,stream>>>(nm, racc_mean, racc_max);

  const int KK[3] = {50000, 25000, 12500};
  for(int l=0; l<3; l++){
    k_deg<<<NB_N,256,0,stream>>>(nm, row_ptr, col, dinv);
    const float* xin = (l == 0) ? x : bufB;
    k_gemm<<<dim3((NN+63)/64, 2),256,0,stream>>>(xin, W[l], bufA);
    k_agg<<<NB_E,256,0,stream>>>(bufA, dinv, row_ptr, col, bb[l], wsc[l], bufB, pbuf);
    k_score<<<NB_N,256,0,stream>>>(pbuf, dinv, row_ptr, col, bsc[l], score, key);
    hipMemsetAsync(hist, 0, (size_t)2*65536*4, stream);
    k_hist_hi<<<NB_N,256,0,stream>>>(key, hist);
    k_pick<<<1,256,0,stream>>>(hist, state, KK[l], 0);
    k_hist_lo<<<NB_N,256,0,stream>>>(key, state, hist + 65536);
    k_pick<<<1,256,0,stream>>>(hist + 65536, state, 0, 1);
    k_maskA<<<NB_N,256,0,stream>>>(key, state, bcnt);
    k_exscan<<<1,512,0,stream>>>(bcnt, NB_N);
    k_maskC<<<NB_N,256,0,stream>>>(key, score, bcnt, state, bufB, nm, racc_mean, racc_max, l);
  }
  k_mlp<<<1,256,0,stream>>>(racc_mean, racc_max, M1, bm1, M2, bm2, M3, bm3, out);
}

// Round 2
// 1070.748 us; speedup vs baseline: 1.0721x; 1.0721x over previous
//
#include <hip/hip_runtime.h>
#include <cstdint>
#include <cstddef>

#define NN 100000
#define EE 1600000
#define HH 128
#define NB_N 391   // ceil(NN/256)
#define NB_E 6250  // ceil(EE/256)

static __device__ __forceinline__ unsigned fsort_(float f){
  unsigned u = __float_as_uint(f);
  return (u & 0x80000000u) ? ~u : (u | 0x80000000u);
}
static __device__ __forceinline__ float unfsort_(unsigned u){
  unsigned v = (u & 0x80000000u) ? (u & 0x7FFFFFFFu) : ~u;
  return __uint_as_float(v);
}
// round-to-nearest-even f32 -> bf16 bits
static __device__ __forceinline__ unsigned bfbits_(float f){
  unsigned u = __float_as_uint(f);
  return (u + 0x7FFFu + ((u >> 16) & 1u)) >> 16;
}
static __device__ __forceinline__ unsigned bfpack_(float f0, float f1){
  return bfbits_(f0) | (bfbits_(f1) << 16);
}
static __device__ __forceinline__ float bflo_(unsigned u){ return __uint_as_float(u << 16); }
static __device__ __forceinline__ float bfhi_(unsigned u){ return __uint_as_float(u & 0xFFFF0000u); }

// ---------- edge dtype probe (int64 vs int32 layout) ----------
__global__ void k_edgeflag(const int* __restrict__ ei, unsigned* __restrict__ state){
  int t = threadIdx.x; // 64 threads
  int v = ei[2*t + 1];
  unsigned long long m = __ballot(v != 0);
  if(t == 0) state[8] = (m == 0ull) ? 1u : 0u; // 1 => int64 layout
}
// edge normalize + fused degree count
__global__ void k_edgecopy(const int* __restrict__ ei, const unsigned* __restrict__ state,
                           int* __restrict__ esrc, int* __restrict__ edst,
                           int* __restrict__ cnt){
  int e = blockIdx.x*256 + threadIdx.x;
  if(e >= EE) return;
  int s, d;
  if(state[8]){
    s = ei[2*e];
    d = ei[2*EE + 2*e];
  } else {
    s = ei[e];
    d = ei[EE + e];
  }
  esrc[e] = s;
  edst[e] = d;
  atomicAdd(&cnt[d], 1);
}

// ---------- init ----------
__global__ void k_init(float* __restrict__ nm, float* __restrict__ racc_mean,
                       unsigned* __restrict__ racc_max){
  int i = blockIdx.x*256 + threadIdx.x;
  if(i < NN) nm[i] = 1.f;
  if(i < 3*HH){ racc_mean[i] = 0.f; racc_max[i] = fsort_(-1e30f); }
}

// ---------- CSR build ----------
__global__ void k_blocksum(const int* __restrict__ cnt, int* __restrict__ bsum){
  __shared__ int sm[256];
  int i = blockIdx.x*256 + threadIdx.x;
  sm[threadIdx.x] = (i < NN) ? cnt[i] : 0;
  __syncthreads();
  for(int off=128; off>0; off>>=1){
    if(threadIdx.x < off) sm[threadIdx.x] += sm[threadIdx.x+off];
    __syncthreads();
  }
  if(threadIdx.x == 0) bsum[blockIdx.x] = sm[0];
}
__global__ void k_exscan(int* __restrict__ data, int nb){
  __shared__ int sm[512];
  int t = threadIdx.x;
  int orig = (t < nb) ? data[t] : 0;
  sm[t] = orig;
  __syncthreads();
  for(int off=1; off<512; off<<=1){
    int v = (t >= off) ? sm[t-off] : 0;
    __syncthreads();
    sm[t] += v;
    __syncthreads();
  }
  if(t < nb) data[t] = sm[t] - orig;
}
__global__ void k_scanC(const int* __restrict__ cnt, const int* __restrict__ boff,
                        int* __restrict__ row_ptr, int* __restrict__ fill){
  __shared__ int sm[256];
  int t = threadIdx.x;
  int i = blockIdx.x*256 + t;
  int orig = (i < NN) ? cnt[i] : 0;
  sm[t] = orig;
  __syncthreads();
  for(int off=1; off<256; off<<=1){
    int v = (t >= off) ? sm[t-off] : 0;
    __syncthreads();
    sm[t] += v;
    __syncthreads();
  }
  if(i < NN){ row_ptr[i] = boff[blockIdx.x] + sm[t] - orig; fill[i] = 0; }
  if(i == 0) row_ptr[NN] = EE;
}
__global__ void k_fill(const int* __restrict__ src, const int* __restrict__ dst,
                       const int* __restrict__ row_ptr, int* __restrict__ fill,
                       int* __restrict__ col){
  int e = blockIdx.x*256 + threadIdx.x;
  if(e < EE){
    int d = dst[e];
    int pos = atomicAdd(&fill[d], 1);
    col[row_ptr[d] + pos] = src[e];
  }
}

// ---------- per-layer kernels ----------
__global__ void k_deg(const float* __restrict__ nm, const int* __restrict__ row_ptr,
                      const int* __restrict__ col, float* __restrict__ dinv){
  int i = blockIdx.x*256 + threadIdx.x;
  if(i >= NN) return;
  float d = 0.f;
  if(nm[i] > 0.f){
    int e0 = row_ptr[i], e1 = row_ptr[i+1];
    float s = 1.f;
    for(int e=e0; e<e1; e++) s += nm[col[e]];
    d = s;
  }
  dinv[i] = (d > 0.f) ? (1.f/sqrtf(d)) : 0.f;
}

// y16 = bf16(x @ W)  (N x 128 @ 128 x 128, fp32 accumulate, 64x64 tile, 4x4 microtile)
// dead 64-row blocks (all dinv==0) are skipped: their y rows are never read.
__global__ __launch_bounds__(256) void k_gemm(const float* __restrict__ x,
                                              const float* __restrict__ W,
                                              const float* __restrict__ dinv,
                                              unsigned short* __restrict__ y16){
  __shared__ float sX[16][68];
  __shared__ float sW[16][64];
  __shared__ int alive;
  int row0 = blockIdx.x*64, col0 = blockIdx.y*64;
  int t = threadIdx.x;
  if(t == 0) alive = 0;
  __syncthreads();
  if(t < 64){
    int gr = row0 + t;
    if(gr < NN && dinv[gr] != 0.f) alive = 1;
  }
  __syncthreads();
  if(!alive) return;
  int tx = t & 15, ty = t >> 4;
  float acc[4][4] = {{0.f}};
  for(int kb=0; kb<HH; kb+=16){
    #pragma unroll
    for(int j=0;j<4;j++){
      int r = (t>>4) + j*16;
      int k = t & 15;
      int gr = row0 + r;
      sX[k][r] = (gr < NN) ? x[(size_t)gr*HH + kb + k] : 0.f;
    }
    #pragma unroll
    for(int j=0;j<4;j++){
      int k = (t>>6) + j*4;
      int c = t & 63;
      sW[k][c] = W[(size_t)(kb+k)*HH + col0 + c];
    }
    __syncthreads();
    #pragma unroll
    for(int k=0;k<16;k++){
      float4 xv = *(const float4*)&sX[k][ty*4];
      float4 wv = *(const float4*)&sW[k][tx*4];
      float xs[4] = {xv.x, xv.y, xv.z, xv.w};
      float wsv[4] = {wv.x, wv.y, wv.z, wv.w};
      #pragma unroll
      for(int a=0;a<4;a++)
        #pragma unroll
        for(int b=0;b<4;b++)
          acc[a][b] += xs[a]*wsv[b];
    }
    __syncthreads();
  }
  #pragma unroll
  for(int a=0;a<4;a++){
    int gr = row0 + ty*4 + a;
    if(gr < NN){
      uint2 o;
      o.x = bfpack_(acc[a][0], acc[a][1]);
      o.y = bfpack_(acc[a][2], acc[a][3]);
      *(uint2*)&y16[(size_t)gr*HH + col0 + tx*4] = o;
    }
  }
}

// h = relu(dinv_i * sum_s dinv_s*y_s + dinv_i^2*y_i + b); p = h . ws
// 16 lanes per dst node, 8 bf16 (16 B) per lane per gathered row
__global__ __launch_bounds__(256) void k_agg(const unsigned short* __restrict__ y16,
                     const float* __restrict__ dinv,
                     const int* __restrict__ row_ptr, const int* __restrict__ col,
                     const float* __restrict__ bias, const float* __restrict__ wsc,
                     float* __restrict__ h, float* __restrict__ p){
  int gid = blockIdx.x*256 + threadIdx.x;
  int node = gid >> 4;
  int lane = gid & 15;
  if(node >= NN) return;
  float di = dinv[node];
  if(di == 0.f) return;
  float a0=0,a1=0,a2=0,a3=0,a4=0,a5=0,a6=0,a7=0;
  int e0 = row_ptr[node], e1 = row_ptr[node+1];
  for(int e=e0; e<e1; e++){
    int s = col[e];
    float ds = dinv[s];
    if(ds != 0.f){
      uint4 v = ((const uint4*)(y16 + (size_t)s*HH))[lane];
      a0 += ds*bflo_(v.x); a1 += ds*bfhi_(v.x);
      a2 += ds*bflo_(v.y); a3 += ds*bfhi_(v.y);
      a4 += ds*bflo_(v.z); a5 += ds*bfhi_(v.z);
      a6 += ds*bflo_(v.w); a7 += ds*bfhi_(v.w);
    }
  }
  uint4 sv = ((const uint4*)(y16 + (size_t)node*HH))[lane];
  const float4* b4 = (const float4*)bias;
  float4 bb0 = b4[2*lane], bb1 = b4[2*lane+1];
  float d2 = di*di;
  float o0 = fmaxf(di*a0 + d2*bflo_(sv.x) + bb0.x, 0.f);
  float o1 = fmaxf(di*a1 + d2*bfhi_(sv.x) + bb0.y, 0.f);
  float o2 = fmaxf(di*a2 + d2*bflo_(sv.y) + bb0.z, 0.f);
  float o3 = fmaxf(di*a3 + d2*bfhi_(sv.y) + bb0.w, 0.f);
  float o4 = fmaxf(di*a4 + d2*bflo_(sv.z) + bb1.x, 0.f);
  float o5 = fmaxf(di*a5 + d2*bfhi_(sv.z) + bb1.y, 0.f);
  float o6 = fmaxf(di*a6 + d2*bflo_(sv.w) + bb1.z, 0.f);
  float o7 = fmaxf(di*a7 + d2*bfhi_(sv.w) + bb1.w, 0.f);
  float4* hr = (float4*)(h + (size_t)node*HH);
  hr[2*lane]   = make_float4(o0,o1,o2,o3);
  hr[2*lane+1] = make_float4(o4,o5,o6,o7);
  const float4* w4 = (const float4*)wsc;
  float4 w0 = w4[2*lane], w1 = w4[2*lane+1];
  float pp = o0*w0.x + o1*w0.y + o2*w0.z + o3*w0.w
           + o4*w1.x + o5*w1.y + o6*w1.z + o7*w1.w;
  pp += __shfl_xor(pp, 1, 64);
  pp += __shfl_xor(pp, 2, 64);
  pp += __shfl_xor(pp, 4, 64);
  pp += __shfl_xor(pp, 8, 64);
  if(lane == 0) p[node] = pp;
}

// score + fused hi-histogram (hist must be zeroed before)
__global__ void k_score(const float* __restrict__ p, const float* __restrict__ dinv,
                        const int* __restrict__ row_ptr, const int* __restrict__ col,
                        const float* __restrict__ bs, float* __restrict__ score,
                        unsigned* __restrict__ key, unsigned* __restrict__ hist){
  int i = blockIdx.x*256 + threadIdx.x;
  if(i >= NN) return;
  float di = dinv[i];
  if(di == 0.f){ key[i] = 0u; return; }
  float s = 0.f;
  int e0 = row_ptr[i], e1 = row_ptr[i+1];
  for(int e=e0; e<e1; e++){
    int c = col[e];
    float ds = dinv[c];
    if(ds != 0.f) s += ds*p[c];
  }
  float sc = di*s + di*di*p[i] + bs[0];
  score[i] = sc;
  unsigned kv = fsort_(sc);
  key[i] = kv;
  atomicAdd(&hist[kv>>16], 1u);
}

// ---------- radix select (2x16-bit) ----------
__global__ void k_hist_lo(const unsigned* __restrict__ key, const unsigned* __restrict__ state,
                          unsigned* __restrict__ histB){
  int i = blockIdx.x*256 + threadIdx.x;
  if(i < NN){
    unsigned kv = key[i];
    if((kv >> 16) == state[0]) atomicAdd(&histB[kv & 0xFFFFu], 1u);
  }
}
__global__ void k_pick(const unsigned* __restrict__ hist, unsigned* __restrict__ state,
                       int k_in, int mode){
  __shared__ unsigned csum[256];
  int t = threadIdx.x;
  const uint4* h4 = (const uint4*)(hist + t*256);
  unsigned s = 0;
  for(int j=0;j<64;j++){ uint4 v = h4[j]; s += v.x+v.y+v.z+v.w; }
  csum[t] = s;
  __syncthreads();
  for(int off=1; off<256; off<<=1){
    unsigned v = (t+off < 256) ? csum[t+off] : 0u;
    __syncthreads();
    csum[t] += v;
    __syncthreads();
  }
  unsigned k = (mode == 0) ? (unsigned)k_in : state[1];
  unsigned above = csum[t] - s;
  if(above < k && above + s >= k){
    unsigned run = above;
    for(int j=255; j>=0; j--){
      unsigned c = hist[t*256+j];
      if(run + c >= k){
        if(mode == 0){ state[0] = (unsigned)(t*256+j); state[1] = k - run; }
        else { state[2] = (state[0] << 16) | (unsigned)(t*256+j); state[3] = k - run; }
        break;
      }
      run += c;
    }
  }
}

// ---------- tie ranking + mask + gate + readout ----------
__global__ void k_maskA(const unsigned* __restrict__ key, const unsigned* __restrict__ state,
                        int* __restrict__ bcnt){
  __shared__ int c4[4];
  int t = threadIdx.x;
  int i = blockIdx.x*256 + t;
  unsigned T = state[2];
  bool match = (i < NN) && (key[i] == T);
  unsigned long long m = __ballot(match);
  if((t & 63) == 0) c4[t >> 6] = __popcll(m);
  __syncthreads();
  if(t == 0) bcnt[blockIdx.x] = c4[0]+c4[1]+c4[2]+c4[3];
}

__global__ __launch_bounds__(256) void k_maskC(const unsigned* __restrict__ key, const float* __restrict__ score,
                       const int* __restrict__ boff, const unsigned* __restrict__ state,
                       float* __restrict__ h, float* __restrict__ nm,
                       float* __restrict__ racc_mean, unsigned* __restrict__ racc_max, int layer){
  __shared__ float gl[256];
  __shared__ unsigned char slf[256];
  __shared__ int wcnt[4];
  __shared__ float4 red[256];
  int t = threadIdx.x;
  int i = blockIdx.x*256 + t;
  unsigned T = state[2];
  int trem = (int)state[3];
  unsigned kv = (i < NN) ? key[i] : 0u;
  bool match = (kv == T);
  unsigned long long m = __ballot(match);
  int lane = t & 63, wid = t >> 6;
  if(lane == 0) wcnt[wid] = __popcll(m);
  __syncthreads();
  int pre = 0;
  for(int w=0; w<wid; w++) pre += wcnt[w];
  int lrank = __popcll(m & ((1ull << lane) - 1ull));
  int rank = boff[blockIdx.x] + pre + lrank;
  bool sel = (kv > T) || (match && rank < trem);
  float g = 0.f;
  if(sel) g = tanhf(score[i]);
  gl[t] = g;
  slf[t] = sel ? 1 : 0;
  if(i < NN) nm[i] = sel ? 1.f : 0.f;
  __syncthreads();
  int ch = t & 31;
  int nb = t >> 5;
  float mx_=0.f, my_=0.f, mz_=0.f, mw_=0.f;
  float Mx=-1e30f, My=-1e30f, Mz=-1e30f, Mw=-1e30f;
  int base = blockIdx.x*256;
  for(int itr=0; itr<32; itr++){
    int nl = nb + itr*8;
    int node = base + nl;
    if(node < NN && slf[nl]){   // unselected rows never read downstream; skip them
      float gg = gl[nl];
      float4* hp = (float4*)(h + (size_t)node*HH) + ch;
      float4 v = *hp;
      v.x *= gg; v.y *= gg; v.z *= gg; v.w *= gg;
      *hp = v;
      mx_ += v.x; my_ += v.y; mz_ += v.z; mw_ += v.w;
      Mx = fmaxf(Mx, v.x); My = fmaxf(My, v.y);
      Mz = fmaxf(Mz, v.z); Mw = fmaxf(Mw, v.w);
    }
  }
  red[t] = make_float4(mx_,my_,mz_,mw_);
  __syncthreads();
  if(t < 32){
    float4 sacc = red[t];
    for(int j=1;j<8;j++){
      float4 o = red[t + 32*j];
      sacc.x += o.x; sacc.y += o.y; sacc.z += o.z; sacc.w += o.w;
    }
    int d = layer*HH + t*4;
    atomicAdd(&racc_mean[d+0], sacc.x);
    atomicAdd(&racc_mean[d+1], sacc.y);
    atomicAdd(&racc_mean[d+2], sacc.z);
    atomicAdd(&racc_mean[d+3], sacc.w);
  }
  __syncthreads();
  red[t] = make_float4(Mx,My,Mz,Mw);
  __syncthreads();
  if(t < 32){
    float4 sacc = red[t];
    for(int j=1;j<8;j++){
      float4 o = red[t + 32*j];
      sacc.x = fmaxf(sacc.x,o.x); sacc.y = fmaxf(sacc.y,o.y);
      sacc.z = fmaxf(sacc.z,o.z); sacc.w = fmaxf(sacc.w,o.w);
    }
    int d = layer*HH + t*4;
    atomicMax(&racc_max[d+0], fsort_(sacc.x));
    atomicMax(&racc_max[d+1], fsort_(sacc.y));
    atomicMax(&racc_max[d+2], fsort_(sacc.z));
    atomicMax(&racc_max[d+3], fsort_(sacc.w));
  }
}

// ---------- MLP head + log_softmax ----------
__global__ void k_mlp(const float* __restrict__ racc_mean, const unsigned* __restrict__ racc_max,
                      const float* __restrict__ M1, const float* __restrict__ bm1,
                      const float* __restrict__ M2, const float* __restrict__ bm2,
                      const float* __restrict__ M3, const float* __restrict__ bm3,
                      float* __restrict__ out){
  __shared__ float R[256];
  __shared__ float y1[128];
  __shared__ float y2[64];
  __shared__ float y3[16];
  int t = threadIdx.x;
  if(t < 128){
    R[t] = racc_mean[t]/50000.f + racc_mean[128+t]/25000.f + racc_mean[256+t]/12500.f;
    R[128+t] = unfsort_(racc_max[t]) + unfsort_(racc_max[128+t]) + unfsort_(racc_max[256+t]);
  }
  __syncthreads();
  if(t < 128){
    float a = bm1[t];
    for(int d=0; d<256; d++) a += R[d]*M1[d*128+t];
    y1[t] = fmaxf(a, 0.f);
  }
  __syncthreads();
  if(t < 64){
    float a = bm2[t];
    for(int d=0; d<128; d++) a += y1[d]*M2[d*64+t];
    y2[t] = fmaxf(a, 0.f);
  }
  __syncthreads();
  if(t < 10){
    float a = bm3[t];
    for(int d=0; d<64; d++) a += y2[d]*M3[d*10+t];
    y3[t] = a;
  }
  __syncthreads();
  if(t == 0){
    float mx = -1e30f;
    for(int o=0;o<10;o++) mx = fmaxf(mx, y3[o]);
    float s = 0.f;
    for(int o=0;o<10;o++) s += expf(y3[o]-mx);
    float ls = logf(s);
    for(int o=0;o<10;o++) out[o] = y3[o] - mx - ls;
  }
}

extern "C" void kernel_launch(void* const* d_in, const int* in_sizes, int n_in,
                              void* d_out, int out_size, void* d_ws, size_t ws_size,
                              hipStream_t stream){
  (void)in_sizes; (void)n_in; (void)out_size; (void)ws_size;
  const float* x  = (const float*)d_in[0];
  const int*   ei = (const int*)d_in[1];
  const float* W[3]   = {(const float*)d_in[2],  (const float*)d_in[6],  (const float*)d_in[10]};
  const float* bb[3]  = {(const float*)d_in[3],  (const float*)d_in[7],  (const float*)d_in[11]};
  const float* wsc[3] = {(const float*)d_in[4],  (const float*)d_in[8],  (const float*)d_in[12]};
  const float* bsc[3] = {(const float*)d_in[5],  (const float*)d_in[9],  (const float*)d_in[13]};
  const float* M1  = (const float*)d_in[14];
  const float* bm1 = (const float*)d_in[15];
  const float* M2  = (const float*)d_in[16];
  const float* bm2 = (const float*)d_in[17];
  const float* M3  = (const float*)d_in[18];
  const float* bm3 = (const float*)d_in[19];
  float* out = (float*)d_out;

  char* base = (char*)d_ws;
  size_t off = 0;
  auto alloc = [&](size_t bytes)->char*{
    char* ptr = base + off;
    off += (bytes + 511) & ~(size_t)511;
    return ptr;
  };
  unsigned short* bufA = (unsigned short*)alloc((size_t)NN*HH*2);  // y, bf16
  float*    bufB      = (float*)   alloc((size_t)NN*HH*4);         // h, fp32
  int*      col       = (int*)     alloc((size_t)EE*4);
  int*      esrc      = (int*)     alloc((size_t)EE*4);
  int*      edst      = (int*)     alloc((size_t)EE*4);
  int*      row_ptr   = (int*)     alloc((size_t)(NN+1)*4);
  int*      cnt       = (int*)     alloc((size_t)NN*4);
  int*      fill      = (int*)     alloc((size_t)NN*4);
  float*    dinv      = (float*)   alloc((size_t)NN*4);
  float*    nm        = (float*)   alloc((size_t)NN*4);
  float*    pbuf      = (float*)   alloc((size_t)NN*4);
  float*    score     = (float*)   alloc((size_t)NN*4);
  unsigned* key       = (unsigned*)alloc((size_t)NN*4);
  unsigned* hist      = (unsigned*)alloc((size_t)2*65536*4);
  unsigned* state     = (unsigned*)alloc(256);
  int*      bsum      = (int*)     alloc(2048);
  int*      bcnt      = (int*)     alloc(2048);
  float*    racc_mean = (float*)   alloc(3*HH*4);
  unsigned* racc_max  = (unsigned*)alloc(3*HH*4);

  // edge normalize (handles int64 or int32 layout) + fused degree count
  k_edgeflag<<<1,64,0,stream>>>(ei, state);
  hipMemsetAsync(cnt, 0, (size_t)NN*4, stream);
  k_edgecopy<<<NB_E,256,0,stream>>>(ei, state, esrc, edst, cnt);

  // CSR build (by dst)
  k_blocksum<<<NB_N,256,0,stream>>>(cnt, bsum);
  k_exscan<<<1,512,0,stream>>>(bsum, NB_N);
  k_scanC<<<NB_N,256,0,stream>>>(cnt, bsum, row_ptr, fill);
  k_fill<<<NB_E,256,0,stream>>>(esrc, edst, row_ptr, fill, col);
  k_init<<<NB_N,256,0,stream>>>(nm, racc_mean, racc_max);

  const int KK[3] = {50000, 25000, 12500};
  for(int l=0; l<3; l++){
    k_deg<<<NB_N,256,0,stream>>>(nm, row_ptr, col, dinv);
    const float* xin = (l == 0) ? x : bufB;
    k_gemm<<<dim3((NN+63)/64, 2),256,0,stream>>>(xin, W[l], dinv, bufA);
    k_agg<<<NB_E,256,0,stream>>>(bufA, dinv, row_ptr, col, bb[l], wsc[l], bufB, pbuf);
    hipMemsetAsync(hist, 0, (size_t)2*65536*4, stream);
    k_score<<<NB_N,256,0,stream>>>(pbuf, dinv, row_ptr, col, bsc[l], score, key, hist);
    k_pick<<<1,256,0,stream>>>(hist, state, KK[l], 0);
    k_hist_lo<<<NB_N,256,0,stream>>>(key, state, hist + 65536);
    k_pick<<<1,256,0,stream>>>(hist + 65536, state, 0, 1);
    k_maskA<<<NB_N,256,0,stream>>>(key, state, bcnt);
    k_exscan<<<1,512,0,stream>>>(bcnt, NB_N);
    k_maskC<<<NB_N,256,0,stream>>>(key, score, bcnt, state, bufB, nm, racc_mean, racc_max, l);
  }
  k_mlp<<<1,256,0,stream>>>(racc_mean, racc_max, M1, bm1, M2, bm2, M3, bm3, out);
}

// Round 3
// 912.296 us; speedup vs baseline: 1.2584x; 1.1737x over previous
//
#include <hip/hip_runtime.h>
#include <cstdint>
#include <cstddef>

#define NN 100000
#define EE 1600000
#define HH 128
#define NB_N 391    // ceil(NN/256)
#define NB_E 6250   // ceil(EE/256)
#define NBKT 391    // ceil(NN/256) buckets of 256 dst nodes
#define CAP 5120    // staging capacity per bucket (mean 4092, +16 sigma)

static __device__ __forceinline__ unsigned fsort_(float f){
  unsigned u = __float_as_uint(f);
  return (u & 0x80000000u) ? ~u : (u | 0x80000000u);
}
static __device__ __forceinline__ float unfsort_(unsigned u){
  unsigned v = (u & 0x80000000u) ? (u & 0x7FFFFFFFu) : ~u;
  return __uint_as_float(v);
}
// round-to-nearest-even f32 -> bf16 bits
static __device__ __forceinline__ unsigned bfbits_(float f){
  unsigned u = __float_as_uint(f);
  return (u + 0x7FFFu + ((u >> 16) & 1u)) >> 16;
}
static __device__ __forceinline__ unsigned bfpack_(float f0, float f1){
  return bfbits_(f0) | (bfbits_(f1) << 16);
}
static __device__ __forceinline__ float bflo_(unsigned u){ return __uint_as_float(u << 16); }
static __device__ __forceinline__ float bfhi_(unsigned u){ return __uint_as_float(u & 0xFFFF0000u); }

// ---------- edge dtype probe (int64 vs int32 layout) + zero bucket counters ----------
__global__ void k_edgeflag(const int* __restrict__ ei, unsigned* __restrict__ state,
                           unsigned* __restrict__ bktcnt){
  int t = threadIdx.x; // 256 threads
  if(t < 64){
    int v = ei[2*t + 1];
    unsigned long long m = __ballot(v != 0);
    if(t == 0) state[8] = (m == 0ull) ? 1u : 0u; // 1 => int64 layout
  }
  for(int j=t; j<NBKT; j+=256) bktcnt[j] = 0u;
}

// ---------- pass A: bin edges into per-bucket staging (block-contiguous appends) ----------
__global__ __launch_bounds__(256) void k_binA(const int* __restrict__ ei,
                     const unsigned* __restrict__ state,
                     unsigned* __restrict__ bktcnt, unsigned* __restrict__ staging,
                     float* __restrict__ racc_mean, unsigned* __restrict__ racc_max){
  __shared__ unsigned lcnt[NBKT];
  __shared__ unsigned lloc[NBKT];
  int t = threadIdx.x;
  if(blockIdx.x == 0){
    for(int j=t; j<3*HH; j+=256){ racc_mean[j] = 0.f; racc_max[j] = fsort_(-1e30f); }
  }
  for(int j=t; j<NBKT; j+=256){ lcnt[j] = 0u; lloc[j] = 0u; }
  bool i64 = (state[8] != 0u);
  int e0 = blockIdx.x*4096;
  int es[16], ed[16];
  #pragma unroll
  for(int k=0;k<16;k++){
    int e = e0 + k*256 + t;
    int s = -1, d = 0;
    if(e < EE){
      if(i64){ s = ei[2*e]; d = ei[2*EE + 2*e]; }
      else   { s = ei[e];   d = ei[EE + e]; }
    }
    es[k] = s; ed[k] = d;
  }
  __syncthreads();
  #pragma unroll
  for(int k=0;k<16;k++){
    if(es[k] >= 0) atomicAdd(&lcnt[ed[k]>>8], 1u);
  }
  __syncthreads();
  for(int j=t; j<NBKT; j+=256){
    unsigned c = lcnt[j];
    lcnt[j] = c ? atomicAdd(&bktcnt[j], c) : 0u;  // lcnt now holds block's base in bucket
  }
  __syncthreads();
  #pragma unroll
  for(int k=0;k<16;k++){
    if(es[k] >= 0){
      int b = ed[k] >> 8;
      unsigned off = lcnt[b] + atomicAdd(&lloc[b], 1u);
      if(off < CAP)
        staging[(unsigned)b*CAP + off] = (unsigned)es[k] | (((unsigned)(ed[k] & 255)) << 17);
    }
  }
}

// ---------- scan bucket counts -> bucket bases ----------
__global__ void k_scan391(const unsigned* __restrict__ bktcnt, unsigned* __restrict__ bktbase){
  __shared__ unsigned sm[512];
  int t = threadIdx.x;
  unsigned v = (t < NBKT) ? bktcnt[t] : 0u;
  sm[t] = v;
  __syncthreads();
  for(int off=1; off<512; off<<=1){
    unsigned u = (t >= off) ? sm[t-off] : 0u;
    __syncthreads();
    sm[t] += u;
    __syncthreads();
  }
  if(t < NBKT) bktbase[t] = sm[t] - v;
  if(t == NBKT-1) bktbase[NBKT] = sm[t];
}

// ---------- pass B: per-bucket CSR (row_ptr + col + layer-1 dinv) ----------
__global__ __launch_bounds__(256) void k_binB(const unsigned* __restrict__ staging,
                     const unsigned* __restrict__ bktcnt, const unsigned* __restrict__ bktbase,
                     int* __restrict__ row_ptr, int* __restrict__ col,
                     float* __restrict__ dinv){
  __shared__ unsigned hist[256];
  __shared__ unsigned pref[256];
  __shared__ unsigned lfill[256];
  int t = threadIdx.x;
  int b = blockIdx.x;
  unsigned base = bktbase[b];
  unsigned cnt = bktcnt[b]; if(cnt > CAP) cnt = CAP;
  hist[t] = 0u; lfill[t] = 0u;
  __syncthreads();
  const unsigned* st = staging + (unsigned)b*CAP;
  for(unsigned i=t; i<cnt; i+=256) atomicAdd(&hist[st[i]>>17], 1u);
  __syncthreads();
  unsigned h = hist[t];
  pref[t] = h;
  __syncthreads();
  for(int off=1; off<256; off<<=1){
    unsigned u = (t >= off) ? pref[t-off] : 0u;
    __syncthreads();
    pref[t] += u;
    __syncthreads();
  }
  unsigned excl = pref[t] - h;
  int node = b*256 + t;
  if(node < NN){
    row_ptr[node] = (int)(base + excl);
    dinv[node] = rsqrtf(1.f + (float)h);   // layer-1: all nodes alive, deg = 1 + indeg
  }
  if(b == 0 && t == 0) row_ptr[NN] = EE;
  __syncthreads();
  pref[t] = excl;
  __syncthreads();
  for(unsigned i=t; i<cnt; i+=256){
    unsigned w = st[i];
    unsigned dl = w >> 17;
    unsigned pos = base + pref[dl] + atomicAdd(&lfill[dl], 1u);
    col[pos] = (int)(w & 0x1FFFFu);
  }
}

// ---------- per-layer kernels ----------
__global__ void k_deg(const float* __restrict__ nm, const int* __restrict__ row_ptr,
                      const int* __restrict__ col, float* __restrict__ dinv){
  int i = blockIdx.x*256 + threadIdx.x;
  if(i >= NN) return;
  float d = 0.f;
  if(nm[i] > 0.f){
    int e0 = row_ptr[i], e1 = row_ptr[i+1];
    float s = 1.f;
    for(int e=e0; e<e1; e++) s += nm[col[e]];
    d = s;
  }
  dinv[i] = (d > 0.f) ? (1.f/sqrtf(d)) : 0.f;
}

// y16 = bf16(x @ W)  (N x 128 @ 128 x 128, fp32 accumulate, 64x64 tile, 4x4 microtile)
// dead 64-row blocks (all dinv==0) are skipped: their y rows are never read.
__global__ __launch_bounds__(256) void k_gemm(const float* __restrict__ x,
                                              const float* __restrict__ W,
                                              const float* __restrict__ dinv,
                                              unsigned short* __restrict__ y16){
  __shared__ float sX[16][68];
  __shared__ float sW[16][64];
  __shared__ int alive;
  int row0 = blockIdx.x*64, col0 = blockIdx.y*64;
  int t = threadIdx.x;
  if(t == 0) alive = 0;
  __syncthreads();
  if(t < 64){
    int gr = row0 + t;
    if(gr < NN && dinv[gr] != 0.f) alive = 1;
  }
  __syncthreads();
  if(!alive) return;
  int tx = t & 15, ty = t >> 4;
  float acc[4][4] = {{0.f}};
  for(int kb=0; kb<HH; kb+=16){
    #pragma unroll
    for(int j=0;j<4;j++){
      int r = (t>>4) + j*16;
      int k = t & 15;
      int gr = row0 + r;
      sX[k][r] = (gr < NN) ? x[(size_t)gr*HH + kb + k] : 0.f;
    }
    #pragma unroll
    for(int j=0;j<4;j++){
      int k = (t>>6) + j*4;
      int c = t & 63;
      sW[k][c] = W[(size_t)(kb+k)*HH + col0 + c];
    }
    __syncthreads();
    #pragma unroll
    for(int k=0;k<16;k++){
      float4 xv = *(const float4*)&sX[k][ty*4];
      float4 wv = *(const float4*)&sW[k][tx*4];
      float xs[4] = {xv.x, xv.y, xv.z, xv.w};
      float wsv[4] = {wv.x, wv.y, wv.z, wv.w};
      #pragma unroll
      for(int a=0;a<4;a++)
        #pragma unroll
        for(int b=0;b<4;b++)
          acc[a][b] += xs[a]*wsv[b];
    }
    __syncthreads();
  }
  #pragma unroll
  for(int a=0;a<4;a++){
    int gr = row0 + ty*4 + a;
    if(gr < NN){
      uint2 o;
      o.x = bfpack_(acc[a][0], acc[a][1]);
      o.y = bfpack_(acc[a][2], acc[a][3]);
      *(uint2*)&y16[(size_t)gr*HH + col0 + tx*4] = o;
    }
  }
}

// h = relu(dinv_i * sum_s dinv_s*y_s + dinv_i^2*y_i + b); p = h . ws
// 16 lanes per dst node, 8 bf16 (16 B) per lane per gathered row.
// Blocks 0..511 also zero the 2x65536 histogram for this layer's select.
__global__ __launch_bounds__(256) void k_agg(const unsigned short* __restrict__ y16,
                     const float* __restrict__ dinv,
                     const int* __restrict__ row_ptr, const int* __restrict__ col,
                     const float* __restrict__ bias, const float* __restrict__ wsc,
                     float* __restrict__ h, float* __restrict__ p,
                     unsigned* __restrict__ hist){
  if(blockIdx.x < 512) hist[blockIdx.x*256 + threadIdx.x] = 0u;
  int gid = blockIdx.x*256 + threadIdx.x;
  int node = gid >> 4;
  int lane = gid & 15;
  if(node >= NN) return;
  float di = dinv[node];
  if(di == 0.f) return;
  float a0=0,a1=0,a2=0,a3=0,a4=0,a5=0,a6=0,a7=0;
  int e0 = row_ptr[node], e1 = row_ptr[node+1];
  for(int e=e0; e<e1; e++){
    int s = col[e];
    float ds = dinv[s];
    if(ds != 0.f){
      uint4 v = ((const uint4*)(y16 + (size_t)s*HH))[lane];
      a0 += ds*bflo_(v.x); a1 += ds*bfhi_(v.x);
      a2 += ds*bflo_(v.y); a3 += ds*bfhi_(v.y);
      a4 += ds*bflo_(v.z); a5 += ds*bfhi_(v.z);
      a6 += ds*bflo_(v.w); a7 += ds*bfhi_(v.w);
    }
  }
  uint4 sv = ((const uint4*)(y16 + (size_t)node*HH))[lane];
  const float4* b4 = (const float4*)bias;
  float4 bb0 = b4[2*lane], bb1 = b4[2*lane+1];
  float d2 = di*di;
  float o0 = fmaxf(di*a0 + d2*bflo_(sv.x) + bb0.x, 0.f);
  float o1 = fmaxf(di*a1 + d2*bfhi_(sv.x) + bb0.y, 0.f);
  float o2 = fmaxf(di*a2 + d2*bflo_(sv.y) + bb0.z, 0.f);
  float o3 = fmaxf(di*a3 + d2*bfhi_(sv.y) + bb0.w, 0.f);
  float o4 = fmaxf(di*a4 + d2*bflo_(sv.z) + bb1.x, 0.f);
  float o5 = fmaxf(di*a5 + d2*bfhi_(sv.z) + bb1.y, 0.f);
  float o6 = fmaxf(di*a6 + d2*bflo_(sv.w) + bb1.z, 0.f);
  float o7 = fmaxf(di*a7 + d2*bfhi_(sv.w) + bb1.w, 0.f);
  float4* hr = (float4*)(h + (size_t)node*HH);
  hr[2*lane]   = make_float4(o0,o1,o2,o3);
  hr[2*lane+1] = make_float4(o4,o5,o6,o7);
  const float4* w4 = (const float4*)wsc;
  float4 w0 = w4[2*lane], w1 = w4[2*lane+1];
  float pp = o0*w0.x + o1*w0.y + o2*w0.z + o3*w0.w
           + o4*w1.x + o5*w1.y + o6*w1.z + o7*w1.w;
  pp += __shfl_xor(pp, 1, 64);
  pp += __shfl_xor(pp, 2, 64);
  pp += __shfl_xor(pp, 4, 64);
  pp += __shfl_xor(pp, 8, 64);
  if(lane == 0) p[node] = pp;
}

// score + fused hi-histogram (hist zeroed by k_agg)
__global__ void k_score(const float* __restrict__ p, const float* __restrict__ dinv,
                        const int* __restrict__ row_ptr, const int* __restrict__ col,
                        const float* __restrict__ bs, float* __restrict__ score,
                        unsigned* __restrict__ key, unsigned* __restrict__ hist){
  int i = blockIdx.x*256 + threadIdx.x;
  if(i >= NN) return;
  float di = dinv[i];
  if(di == 0.f){ key[i] = 0u; return; }
  float s = 0.f;
  int e0 = row_ptr[i], e1 = row_ptr[i+1];
  for(int e=e0; e<e1; e++){
    int c = col[e];
    float ds = dinv[c];
    if(ds != 0.f) s += ds*p[c];
  }
  float sc = di*s + di*di*p[i] + bs[0];
  score[i] = sc;
  unsigned kv = fsort_(sc);
  key[i] = kv;
  atomicAdd(&hist[kv>>16], 1u);
}

// ---------- radix select (2x16-bit) ----------
__global__ void k_hist_lo(const unsigned* __restrict__ key, const unsigned* __restrict__ state,
                          unsigned* __restrict__ histB){
  int i = blockIdx.x*256 + threadIdx.x;
  if(i < NN){
    unsigned kv = key[i];
    if((kv >> 16) == state[0]) atomicAdd(&histB[kv & 0xFFFFu], 1u);
  }
}
__global__ void k_pick(const unsigned* __restrict__ hist, unsigned* __restrict__ state,
                       int k_in, int mode){
  __shared__ unsigned csum[256];
  int t = threadIdx.x;
  const uint4* h4 = (const uint4*)(hist + t*256);
  unsigned s = 0;
  for(int j=0;j<64;j++){ uint4 v = h4[j]; s += v.x+v.y+v.z+v.w; }
  csum[t] = s;
  __syncthreads();
  for(int off=1; off<256; off<<=1){
    unsigned v = (t+off < 256) ? csum[t+off] : 0u;
    __syncthreads();
    csum[t] += v;
    __syncthreads();
  }
  unsigned k = (mode == 0) ? (unsigned)k_in : state[1];
  unsigned above = csum[t] - s;
  if(above < k && above + s >= k){
    unsigned run = above;
    for(int j=255; j>=0; j--){
      unsigned c = hist[t*256+j];
      if(run + c >= k){
        if(mode == 0){ state[0] = (unsigned)(t*256+j); state[1] = k - run; }
        else { state[2] = (state[0] << 16) | (unsigned)(t*256+j); state[3] = k - run; }
        break;
      }
      run += c;
    }
  }
}

// ---------- mask + gate + readout; self-contained tie ranking ----------
__global__ __launch_bounds__(256) void k_maskC(const unsigned* __restrict__ key, const float* __restrict__ score,
                       const unsigned* __restrict__ state,
                       float* __restrict__ h, float* __restrict__ nm,
                       float* __restrict__ racc_mean, unsigned* __restrict__ racc_max, int layer){
  __shared__ float gl[256];
  __shared__ unsigned char slf[256];
  __shared__ int wcnt[4];
  __shared__ int priorSh;
  __shared__ int redi[256];
  __shared__ float4 red[256];
  int t = threadIdx.x;
  int i = blockIdx.x*256 + t;
  unsigned T = state[2];
  int trem = (int)state[3];
  unsigned kv = (i < NN) ? key[i] : 0u;
  bool match = (kv == T);
  unsigned long long m = __ballot(match);
  int lane = t & 63, wid = t >> 6;
  if(lane == 0) wcnt[wid] = __popcll(m);
  if(t == 0) priorSh = 0;
  __syncthreads();
  int hasMatch = wcnt[0] | wcnt[1] | wcnt[2] | wcnt[3];
  if(hasMatch){   // rare: only blocks containing threshold-tied keys
    int base = blockIdx.x*256;
    int cm = 0;
    for(int j = t*4; j < base; j += 1024){
      uint4 kk = *(const uint4*)&key[j];
      cm += (kk.x==T) + (kk.y==T) + (kk.z==T) + (kk.w==T);
    }
    redi[t] = cm;
    __syncthreads();
    for(int off=128; off>0; off>>=1){
      if(t < off) redi[t] += redi[t+off];
      __syncthreads();
    }
    if(t == 0) priorSh = redi[0];
    __syncthreads();
  }
  int pre = 0;
  for(int w=0; w<wid; w++) pre += wcnt[w];
  int lrank = __popcll(m & ((1ull << lane) - 1ull));
  int rank = priorSh + pre + lrank;
  bool sel = (kv > T) || (match && rank < trem);
  float g = 0.f;
  if(sel) g = tanhf(score[i]);
  gl[t] = g;
  slf[t] = sel ? 1 : 0;
  if(i < NN) nm[i] = sel ? 1.f : 0.f;
  __syncthreads();
  int ch = t & 31;
  int nb = t >> 5;
  float mx_=0.f, my_=0.f, mz_=0.f, mw_=0.f;
  float Mx=-1e30f, My=-1e30f, Mz=-1e30f, Mw=-1e30f;
  int base = blockIdx.x*256;
  for(int itr=0; itr<32; itr++){
    int nl = nb + itr*8;
    int node = base + nl;
    if(node < NN && slf[nl]){   // unselected rows never read downstream; skip them
      float gg = gl[nl];
      float4* hp = (float4*)(h + (size_t)node*HH) + ch;
      float4 v = *hp;
      v.x *= gg; v.y *= gg; v.z *= gg; v.w *= gg;
      *hp = v;
      mx_ += v.x; my_ += v.y; mz_ += v.z; mw_ += v.w;
      Mx = fmaxf(Mx, v.x); My = fmaxf(My, v.y);
      Mz = fmaxf(Mz, v.z); Mw = fmaxf(Mw, v.w);
    }
  }
  red[t] = make_float4(mx_,my_,mz_,mw_);
  __syncthreads();
  if(t < 32){
    float4 sacc = red[t];
    for(int j=1;j<8;j++){
      float4 o = red[t + 32*j];
      sacc.x += o.x; sacc.y += o.y; sacc.z += o.z; sacc.w += o.w;
    }
    int d = layer*HH + t*4;
    atomicAdd(&racc_mean[d+0], sacc.x);
    atomicAdd(&racc_mean[d+1], sacc.y);
    atomicAdd(&racc_mean[d+2], sacc.z);
    atomicAdd(&racc_mean[d+3], sacc.w);
  }
  __syncthreads();
  red[t] = make_float4(Mx,My,Mz,Mw);
  __syncthreads();
  if(t < 32){
    float4 sacc = red[t];
    for(int j=1;j<8;j++){
      float4 o = red[t + 32*j];
      sacc.x = fmaxf(sacc.x,o.x); sacc.y = fmaxf(sacc.y,o.y);
      sacc.z = fmaxf(sacc.z,o.z); sacc.w = fmaxf(sacc.w,o.w);
    }
    int d = layer*HH + t*4;
    atomicMax(&racc_max[d+0], fsort_(sacc.x));
    atomicMax(&racc_max[d+1], fsort_(sacc.y));
    atomicMax(&racc_max[d+2], fsort_(sacc.z));
    atomicMax(&racc_max[d+3], fsort_(sacc.w));
  }
}

// ---------- MLP head + log_softmax ----------
__global__ void k_mlp(const float* __restrict__ racc_mean, const unsigned* __restrict__ racc_max,
                      const float* __restrict__ M1, const float* __restrict__ bm1,
                      const float* __restrict__ M2, const float* __restrict__ bm2,
                      const float* __restrict__ M3, const float* __restrict__ bm3,
                      float* __restrict__ out){
  __shared__ float R[256];
  __shared__ float y1[128];
  __shared__ float y2[64];
  __shared__ float y3[16];
  int t = threadIdx.x;
  if(t < 128){
    R[t] = racc_mean[t]/50000.f + racc_mean[128+t]/25000.f + racc_mean[256+t]/12500.f;
    R[128+t] = unfsort_(racc_max[t]) + unfsort_(racc_max[128+t]) + unfsort_(racc_max[256+t]);
  }
  __syncthreads();
  if(t < 128){
    float a = bm1[t];
    for(int d=0; d<256; d++) a += R[d]*M1[d*128+t];
    y1[t] = fmaxf(a, 0.f);
  }
  __syncthreads();
  if(t < 64){
    float a = bm2[t];
    for(int d=0; d<128; d++) a += y1[d]*M2[d*64+t];
    y2[t] = fmaxf(a, 0.f);
  }
  __syncthreads();
  if(t < 10){
    float a = bm3[t];
    for(int d=0; d<64; d++) a += y2[d]*M3[d*10+t];
    y3[t] = a;
  }
  __syncthreads();
  if(t == 0){
    float mx = -1e30f;
    for(int o=0;o<10;o++) mx = fmaxf(mx, y3[o]);
    float s = 0.f;
    for(int o=0;o<10;o++) s += expf(y3[o]-mx);
    float ls = logf(s);
    for(int o=0;o<10;o++) out[o] = y3[o] - mx - ls;
  }
}

extern "C" void kernel_launch(void* const* d_in, const int* in_sizes, int n_in,
                              void* d_out, int out_size, void* d_ws, size_t ws_size,
                              hipStream_t stream){
  (void)in_sizes; (void)n_in; (void)out_size; (void)ws_size;
  const float* x  = (const float*)d_in[0];
  const int*   ei = (const int*)d_in[1];
  const float* W[3]   = {(const float*)d_in[2],  (const float*)d_in[6],  (const float*)d_in[10]};
  const float* bb[3]  = {(const float*)d_in[3],  (const float*)d_in[7],  (const float*)d_in[11]};
  const float* wsc[3] = {(const float*)d_in[4],  (const float*)d_in[8],  (const float*)d_in[12]};
  const float* bsc[3] = {(const float*)d_in[5],  (const float*)d_in[9],  (const float*)d_in[13]};
  const float* M1  = (const float*)d_in[14];
  const float* bm1 = (const float*)d_in[15];
  const float* M2  = (const float*)d_in[16];
  const float* bm2 = (const float*)d_in[17];
  const float* M3  = (const float*)d_in[18];
  const float* bm3 = (const float*)d_in[19];
  float* out = (float*)d_out;

  char* base = (char*)d_ws;
  size_t off = 0;
  auto alloc = [&](size_t bytes)->char*{
    char* ptr = base + off;
    off += (bytes + 511) & ~(size_t)511;
    return ptr;
  };
  unsigned short* bufA = (unsigned short*)alloc((size_t)NN*HH*2);  // y, bf16
  float*    bufB      = (float*)   alloc((size_t)NN*HH*4);         // h, fp32
  int*      col       = (int*)     alloc((size_t)EE*4);
  unsigned* staging   = (unsigned*)alloc((size_t)NBKT*CAP*4);
  int*      row_ptr   = (int*)     alloc((size_t)(NN+1)*4);
  float*    dinv      = (float*)   alloc((size_t)NN*4);
  float*    nm        = (float*)   alloc((size_t)NN*4);
  float*    pbuf      = (float*)   alloc((size_t)NN*4);
  float*    score     = (float*)   alloc((size_t)NN*4);
  unsigned* key       = (unsigned*)alloc((size_t)NN*4);
  unsigned* hist      = (unsigned*)alloc((size_t)2*65536*4);
  unsigned* bktcnt    = (unsigned*)alloc((size_t)(NBKT+1)*4);
  unsigned* bktbase   = (unsigned*)alloc((size_t)(NBKT+1)*4);
  unsigned* state     = (unsigned*)alloc(256);
  float*    racc_mean = (float*)   alloc(3*HH*4);
  unsigned* racc_max  = (unsigned*)alloc(3*HH*4);

  // CSR build: probe layout -> bucket-bin -> scan -> per-bucket CSR (+ layer-1 dinv)
  k_edgeflag<<<1,256,0,stream>>>(ei, state, bktcnt);
  k_binA<<<NBKT,256,0,stream>>>(ei, state, bktcnt, staging, racc_mean, racc_max);
  k_scan391<<<1,512,0,stream>>>(bktcnt, bktbase);
  k_binB<<<NBKT,256,0,stream>>>(staging, bktcnt, bktbase, row_ptr, col, dinv);

  const int KK[3] = {50000, 25000, 12500};
  for(int l=0; l<3; l++){
    if(l) k_deg<<<NB_N,256,0,stream>>>(nm, row_ptr, col, dinv);
    const float* xin = (l == 0) ? x : bufB;
    k_gemm<<<dim3((NN+63)/64, 2),256,0,stream>>>(xin, W[l], dinv, bufA);
    k_agg<<<NB_E,256,0,stream>>>(bufA, dinv, row_ptr, col, bb[l], wsc[l], bufB, pbuf, hist);
    k_score<<<NB_N,256,0,stream>>>(pbuf, dinv, row_ptr, col, bsc[l], score, key, hist);
    k_pick<<<1,256,0,stream>>>(hist, state, KK[l], 0);
    k_hist_lo<<<NB_N,256,0,stream>>>(key, state, hist + 65536);
    k_pick<<<1,256,0,stream>>>(hist + 65536, state, 0, 1);
    k_maskC<<<NB_N,256,0,stream>>>(key, score, state, bufB, nm, racc_mean, racc_max, l);
  }
  k_mlp<<<1,256,0,stream>>>(racc_mean, racc_max, M1, bm1, M2, bm2, M3, bm3, out);
}